// Round 4
// baseline (501.053 us; speedup 1.0000x reference)
//
#include <hip/hip_runtime.h>
#include <cstdint>
#include <cstddef>

typedef _Float16 half8 __attribute__((ext_vector_type(8)));
typedef float floatx4 __attribute__((ext_vector_type(4)));

constexpr int N = 16384;
constexpr int H = 4096;
constexpr int E = 64;
constexpr int BM = 64;            // rows per block (4 row-groups x 16)
constexpr int NITER = 64;         // K iters per wave (2048 / 32)
constexpr float XSCALE = 2048.0f;                      // 2^11
constexpr float WSCALE = 4096.0f;                      // 2^12
constexpr float DESCALE = 1.0f / (2048.0f * 4096.0f);  // 2^-23

// ---------------- W split prekernel: W (f32) -> Whi + Wlo (f16), scaled by 2^12
__global__ __launch_bounds__(256) void wsplit_kernel(const float* __restrict__ W,
                                                     _Float16* __restrict__ Whi,
                                                     _Float16* __restrict__ Wlo) {
  int i = blockIdx.x * 256 + threadIdx.x;
  if (i >= E * H) return;
  float w = W[i] * WSCALE;
  _Float16 hi = (_Float16)w;
  _Float16 lo = (_Float16)(w - (float)hi);
  Whi[i] = hi;
  Wlo[i] = lo;
}

// split 8 f32 x-values (scaled by 2^11) into f16 hi/lo fragments
__device__ __forceinline__ void cvt_split(const float4& a, const float4& b,
                                          half8& hi, half8& lo) {
  float f[8] = {a.x, a.y, a.z, a.w, b.x, b.y, b.z, b.w};
#pragma unroll
  for (int i = 0; i < 8; ++i) {
    float s = f[i] * XSCALE;
    _Float16 h = (_Float16)s;
    _Float16 l = (_Float16)(s - (float)h);
    hi[i] = h;
    lo[i] = l;
  }
}

// One K=32 chunk held in registers: 2 x-float4 + 8 W-half8 = 40 VGPRs.
struct Chunk {
  float4 xa, xb;
  half8 h0, h1, h2, h3;
  half8 l0, l1, l2, l3;
};

__device__ __forceinline__ void load_chunk(Chunk& ck, const float* xp,
                                           const _Float16* wh,
                                           const _Float16* wl, int col) {
  // W first (L2, short latency), x after (HBM, long) — in-order vmcnt
  // retirement then never queues the short-latency W behind a longer x.
  ck.h0 = *(const half8*)(wh + (size_t)0 * 16 * H + col);
  ck.h1 = *(const half8*)(wh + (size_t)1 * 16 * H + col);
  ck.h2 = *(const half8*)(wh + (size_t)2 * 16 * H + col);
  ck.h3 = *(const half8*)(wh + (size_t)3 * 16 * H + col);
  ck.l0 = *(const half8*)(wl + (size_t)0 * 16 * H + col);
  ck.l1 = *(const half8*)(wl + (size_t)1 * 16 * H + col);
  ck.l2 = *(const half8*)(wl + (size_t)2 * 16 * H + col);
  ck.l3 = *(const half8*)(wl + (size_t)3 * 16 * H + col);
  ck.xa = *(const float4*)(xp + col);
  ck.xb = *(const float4*)(xp + col + 4);
}

__device__ __forceinline__ void consume(const Chunk& ck, floatx4& acc0,
                                        floatx4& acc1, floatx4& acc2,
                                        floatx4& acc3) {
  half8 ahi, alo;
  cvt_split(ck.xa, ck.xb, ahi, alo);
  acc0 = __builtin_amdgcn_mfma_f32_16x16x32_f16(alo, ck.h0, acc0, 0, 0, 0);
  acc1 = __builtin_amdgcn_mfma_f32_16x16x32_f16(alo, ck.h1, acc1, 0, 0, 0);
  acc2 = __builtin_amdgcn_mfma_f32_16x16x32_f16(alo, ck.h2, acc2, 0, 0, 0);
  acc3 = __builtin_amdgcn_mfma_f32_16x16x32_f16(alo, ck.h3, acc3, 0, 0, 0);
  acc0 = __builtin_amdgcn_mfma_f32_16x16x32_f16(ahi, ck.l0, acc0, 0, 0, 0);
  acc1 = __builtin_amdgcn_mfma_f32_16x16x32_f16(ahi, ck.l1, acc1, 0, 0, 0);
  acc2 = __builtin_amdgcn_mfma_f32_16x16x32_f16(ahi, ck.l2, acc2, 0, 0, 0);
  acc3 = __builtin_amdgcn_mfma_f32_16x16x32_f16(ahi, ck.l3, acc3, 0, 0, 0);
  acc0 = __builtin_amdgcn_mfma_f32_16x16x32_f16(ahi, ck.h0, acc0, 0, 0, 0);
  acc1 = __builtin_amdgcn_mfma_f32_16x16x32_f16(ahi, ck.h1, acc1, 0, 0, 0);
  acc2 = __builtin_amdgcn_mfma_f32_16x16x32_f16(ahi, ck.h2, acc2, 0, 0, 0);
  acc3 = __builtin_amdgcn_mfma_f32_16x16x32_f16(ahi, ck.h3, acc3, 0, 0, 0);
}

// 256 blocks x 512 threads. Block = 64 rows. Wave wv: row-group rb=(wv&3)*16,
// K-half kh=wv>>2 (K range kh*2048 .. +2048). No LDS in the main loop — both
// streams go global->VGPR with an explicit 2-chunk register double buffer so
// the compiler emits precise per-register vmcnt(N) waits (no LDS-DMA alias
// full-drain hazard).
__global__ __launch_bounds__(512, 2) void router_kernel(
    const float* __restrict__ x,
    const _Float16* __restrict__ Whi,
    const _Float16* __restrict__ Wlo,
    float* __restrict__ out_scores,
    float* __restrict__ out_w,
    float* __restrict__ out_i) {
  __shared__ float red[2][BM][E];  // 32 KB

  const int tid = threadIdx.x;
  const int wv = tid >> 6;
  const int lane = tid & 63;
  const int c = lane & 15;   // A row / B expert-within-group / C col
  const int q = lane >> 4;   // k-subchunk, and C row-group
  const int rb = (wv & 3) << 4;
  const int kh = wv >> 2;
  const int r0 = blockIdx.x * BM;

  const size_t kb = (size_t)kh * 2048 + q * 8;
  const float* xp = x + (size_t)(r0 + rb + c) * H + kb;
  const _Float16* whp = Whi + (size_t)c * H + kb;
  const _Float16* wlp = Wlo + (size_t)c * H + kb;

  floatx4 acc0 = {0.f, 0.f, 0.f, 0.f};
  floatx4 acc1 = acc0, acc2 = acc0, acc3 = acc0;

  Chunk A, B;
  load_chunk(A, xp, whp, wlp, 0);
  load_chunk(B, xp, whp, wlp, 32);

  for (int it = 0; it < NITER; it += 2) {
    // clamped prefetch columns (tail reloads a live column — L1/L2 hit, unused)
    const int c2 = (it + 2 < NITER) ? (it + 2) * 32 : it * 32;
    const int c3 = (it + 3 < NITER) ? (it + 3) * 32 : it * 32;
    consume(A, acc0, acc1, acc2, acc3);
    load_chunk(A, xp, whp, wlp, c2);
    consume(B, acc0, acc1, acc2, acc3);
    load_chunk(B, xp, whp, wlp, c3);
  }

  // ---- reduce the 2 K-halves via LDS, then per-row softmax/top2 ----
#pragma unroll
  for (int r = 0; r < 4; ++r) {
    const int row = rb + q * 4 + r;
    float* rp = &red[kh][row][0];
    rp[0 * 16 + c] = acc0[r];
    rp[1 * 16 + c] = acc1[r];
    rp[2 * 16 + c] = acc2[r];
    rp[3 * 16 + c] = acc3[r];
  }
  __syncthreads();

  // 8 waves x 8 rows; lane = expert (E == 64 == wave width)
  for (int row = wv * 8; row < wv * 8 + 8; ++row) {
    float v = red[0][row][lane] + red[1][row][lane];
    v *= DESCALE;
    // softmax
    float m = v;
#pragma unroll
    for (int o = 32; o > 0; o >>= 1) m = fmaxf(m, __shfl_xor(m, o));
    float ev = __expf(v - m);
    float ssum = ev;
#pragma unroll
    for (int o = 32; o > 0; o >>= 1) ssum += __shfl_xor(ssum, o);
    out_scores[(size_t)(r0 + row) * E + lane] = ev / ssum;
    // top-2 butterfly with (value desc, index asc) order — matches lax.top_k
    float v1 = v;
    int i1 = lane;
    float v2 = -3.4e38f;
    int i2 = E;
#pragma unroll
    for (int o = 32; o > 0; o >>= 1) {
      float w1 = __shfl_xor(v1, o);
      int j1 = __shfl_xor(i1, o);
      float w2 = __shfl_xor(v2, o);
      int j2 = __shfl_xor(i2, o);
      bool firstBetter = (v1 > w1) || (v1 == w1 && i1 < j1);
      float t1, t2;
      int ti1, ti2;
      if (firstBetter) {
        t1 = v1; ti1 = i1;
        bool sec = (v2 > w1) || (v2 == w1 && i2 < j1);
        t2 = sec ? v2 : w1;
        ti2 = sec ? i2 : j1;
      } else {
        t1 = w1; ti1 = j1;
        bool sec = (w2 > v1) || (w2 == v1 && j2 < i1);
        t2 = sec ? w2 : v1;
        ti2 = sec ? j2 : i1;
      }
      v1 = t1; i1 = ti1; v2 = t2; i2 = ti2;
    }
    if (lane == 0) {
      float e1 = __expf(v1 - m);
      float e2 = __expf(v2 - m);
      float inv = 1.0f / (e1 + e2);
      size_t o2 = (size_t)(r0 + row) * 2;
      out_w[o2] = e1 * inv;
      out_w[o2 + 1] = e2 * inv;
      out_i[o2] = (float)i1;
      out_i[o2 + 1] = (float)i2;
    }
  }
}

extern "C" void kernel_launch(void* const* d_in, const int* in_sizes, int n_in,
                              void* d_out, int out_size, void* d_ws, size_t ws_size,
                              hipStream_t stream) {
  const float* x = (const float*)d_in[0];
  const float* W = (const float*)d_in[1];
  float* out = (float*)d_out;
  float* out_scores = out;                  // [N, 64]
  float* out_w = out + (size_t)N * E;       // [N, 2]
  float* out_i = out_w + (size_t)N * 2;     // [N, 2] (indices as floats)
  _Float16* Whi = (_Float16*)d_ws;
  _Float16* Wlo = Whi + (size_t)E * H;      // 1 MB total in ws

  wsplit_kernel<<<(E * H + 255) / 256, 256, 0, stream>>>(W, Whi, Wlo);
  router_kernel<<<N / BM, 512, 0, stream>>>(x, Whi, Wlo, out_scores, out_w, out_i);
}

// Round 5
// 390.388 us; speedup vs baseline: 1.2835x; 1.2835x over previous
//
#include <hip/hip_runtime.h>
#include <cstdint>
#include <cstddef>

typedef _Float16 half8 __attribute__((ext_vector_type(8)));
typedef float floatx4 __attribute__((ext_vector_type(4)));

constexpr int N = 16384;
constexpr int H = 4096;
constexpr int E = 64;
constexpr int BM = 64;            // rows per block
constexpr int KS = 2;             // split-K factor (blocks per row-tile)
constexpr int KPB = H / KS;       // 2048 K per block
constexpr int BK = 64;            // K per stage
constexpr int NST = KPB / BK;     // 32 stages
constexpr float XSCALE = 2048.0f;                      // 2^11
constexpr float WSCALE = 4096.0f;                      // 2^12
constexpr float DESCALE = 1.0f / (2048.0f * 4096.0f);  // 2^-23

// Stage buffer (32 KB), double buffered (64 KB):
//   x   [0,     16384)  64 rows x 256 B;  16B-seg swizzle phys = log ^ (row&7)
//   Whi [16384, 24576)  64 experts x 128 B; phys = log ^ (e&7)
//   Wlo [24576, 32768)
constexpr int HOFF = 16384;
constexpr int LOFF = 24576;
constexpr int BUFSZ = 32768;

__device__ __forceinline__ void async16(const void* g, void* l) {
  __builtin_amdgcn_global_load_lds(
      (const __attribute__((address_space(1))) void*)g,
      (__attribute__((address_space(3))) void*)l,
      16, 0, 0);
}

// ---------------- W split prekernel: W (f32) -> Whi + Wlo (f16), scaled by 2^12
__global__ __launch_bounds__(256) void wsplit_kernel(const float* __restrict__ W,
                                                     _Float16* __restrict__ Whi,
                                                     _Float16* __restrict__ Wlo) {
  int i = blockIdx.x * 256 + threadIdx.x;
  if (i >= E * H) return;
  float w = W[i] * WSCALE;
  _Float16 hi = (_Float16)w;
  _Float16 lo = (_Float16)(w - (float)hi);
  Whi[i] = hi;
  Wlo[i] = lo;
}

// split 8 f32 x-values (scaled by 2^11) into f16 hi/lo fragments
__device__ __forceinline__ void cvt_split(const float4& a, const float4& b,
                                          half8& hi, half8& lo) {
  float f[8] = {a.x, a.y, a.z, a.w, b.x, b.y, b.z, b.w};
#pragma unroll
  for (int i = 0; i < 8; ++i) {
    float s = f[i] * XSCALE;
    _Float16 h = (_Float16)s;
    _Float16 l = (_Float16)(s - (float)h);
    hi[i] = h;
    lo[i] = l;
  }
}

// GEMM kernel (split-K): grid = (N/BM)*KS = 512 blocks x 512 threads.
// Block: rowtile = bid>>1 (64 rows), ks = bid&1 (K half). m97 structure:
// one __syncthreads per stage; global_load_lds staging; ds_read fragments.
// Wave wv: row-group rb=(wv&3)*16, K-subhalf kh=wv>>2 of each 64-wide stage.
__global__ __launch_bounds__(512, 4) void gemm_kernel(
    const float* __restrict__ x,
    const _Float16* __restrict__ Whi,
    const _Float16* __restrict__ Wlo,
    float* __restrict__ part) {
  __shared__ __align__(16) char smem[2 * BUFSZ];

  const int tid = threadIdx.x;
  const int wv = tid >> 6;
  const int lane = tid & 63;
  const int c = lane & 15;
  const int q = lane >> 4;
  const int rowtile = blockIdx.x >> 1;
  const int ks = blockIdx.x & 1;
  const int r0 = rowtile * BM;
  const int k0 = ks * KPB;

  // ---- staging addresses: 4 async16 per thread per stage ----
  // x (16 KB = 2 loads): load i covers rows 32i..32i+31; t -> row 32i+(t>>4),
  // phys seg t&15, log = phys ^ (row&7)
  const int xrA = tid >> 4;
  const int xrB = 32 + xrA;
  const float* gxA = x + (size_t)(r0 + xrA) * H + k0 + (((tid & 15) ^ (xrA & 7)) * 4);
  const float* gxB = x + (size_t)(r0 + xrB) * H + k0 + (((tid & 15) ^ (xrB & 7)) * 4);
  // Whi/Wlo (8 KB each = 1 load): t -> expert t>>3, phys seg t&7, log = phys^(e&7)
  const int we = tid >> 3;
  const int wlog = (tid & 7) ^ (we & 7);
  const _Float16* gwh = Whi + (size_t)we * H + k0 + wlog * 8;
  const _Float16* gwl = Wlo + (size_t)we * H + k0 + wlog * 8;
  const int xdA = tid * 16;
  const int xdB = 8192 + tid * 16;
  const int wd = tid * 16;

  // ---- fragment LDS byte offsets ----
  const int kh = wv >> 2;
  const int rb = (wv & 3) << 4;
  const int fr = rb + c;
  const int sA = 8 * kh + 2 * q;
  const int xo0 = fr * 256 + ((sA ^ (fr & 7)) * 16);
  const int xo1 = fr * 256 + (((sA + 1) ^ (fr & 7)) * 16);
  const int wph = ((4 * kh + q) ^ (c & 7)) * 16;
  const int wo0 = (0 * 16 + c) * 128 + wph;
  const int wo1 = (1 * 16 + c) * 128 + wph;
  const int wo2 = (2 * 16 + c) * 128 + wph;
  const int wo3 = (3 * 16 + c) * 128 + wph;

  auto stage = [&](int s, int b) {
    const int kc = s * BK;
    char* base = smem + b * BUFSZ;
    async16(gxA + kc, base + xdA);
    async16(gxB + kc, base + xdB);
    async16(gwh + kc, base + HOFF + wd);
    async16(gwl + kc, base + LOFF + wd);
  };

  floatx4 acc0 = {0.f, 0.f, 0.f, 0.f};
  floatx4 acc1 = acc0, acc2 = acc0, acc3 = acc0;

  stage(0, 0);
  for (int s = 0; s < NST; ++s) {
    const int b = s & 1;
    __syncthreads();                       // drains stage s's DMA (m97 pattern)
    if (s + 1 < NST) stage(s + 1, b ^ 1);  // next stage in flight during compute

    const char* bb = smem + b * BUFSZ;
    float4 xa = *(const float4*)(bb + xo0);
    float4 xb4 = *(const float4*)(bb + xo1);
    half8 h0 = *(const half8*)(bb + HOFF + wo0);
    half8 h1 = *(const half8*)(bb + HOFF + wo1);
    half8 h2 = *(const half8*)(bb + HOFF + wo2);
    half8 h3 = *(const half8*)(bb + HOFF + wo3);
    half8 l0 = *(const half8*)(bb + LOFF + wo0);
    half8 l1 = *(const half8*)(bb + LOFF + wo1);
    half8 l2 = *(const half8*)(bb + LOFF + wo2);
    half8 l3 = *(const half8*)(bb + LOFF + wo3);

    half8 ahi, alo;
    cvt_split(xa, xb4, ahi, alo);

    acc0 = __builtin_amdgcn_mfma_f32_16x16x32_f16(alo, h0, acc0, 0, 0, 0);
    acc1 = __builtin_amdgcn_mfma_f32_16x16x32_f16(alo, h1, acc1, 0, 0, 0);
    acc2 = __builtin_amdgcn_mfma_f32_16x16x32_f16(alo, h2, acc2, 0, 0, 0);
    acc3 = __builtin_amdgcn_mfma_f32_16x16x32_f16(alo, h3, acc3, 0, 0, 0);
    acc0 = __builtin_amdgcn_mfma_f32_16x16x32_f16(ahi, l0, acc0, 0, 0, 0);
    acc1 = __builtin_amdgcn_mfma_f32_16x16x32_f16(ahi, l1, acc1, 0, 0, 0);
    acc2 = __builtin_amdgcn_mfma_f32_16x16x32_f16(ahi, l2, acc2, 0, 0, 0);
    acc3 = __builtin_amdgcn_mfma_f32_16x16x32_f16(ahi, l3, acc3, 0, 0, 0);
    acc0 = __builtin_amdgcn_mfma_f32_16x16x32_f16(ahi, h0, acc0, 0, 0, 0);
    acc1 = __builtin_amdgcn_mfma_f32_16x16x32_f16(ahi, h1, acc1, 0, 0, 0);
    acc2 = __builtin_amdgcn_mfma_f32_16x16x32_f16(ahi, h2, acc2, 0, 0, 0);
    acc3 = __builtin_amdgcn_mfma_f32_16x16x32_f16(ahi, h3, acc3, 0, 0, 0);
  }

  // ---- reduce the 2 K-subhalves, write block partial to ws ----
  __syncthreads();            // everyone done reading buffers (red aliases them)
  float* red = (float*)smem;  // [2][64][64] = 32 KB
#pragma unroll
  for (int r = 0; r < 4; ++r) {
    const int row = rb + q * 4 + r;
    float* rp = red + (kh * 64 + row) * 64;
    rp[0 * 16 + c] = acc0[r];
    rp[1 * 16 + c] = acc1[r];
    rp[2 * 16 + c] = acc2[r];
    rp[3 * 16 + c] = acc3[r];
  }
  __syncthreads();

  if (wv < 4) {  // 4 waves x 16 rows; lane = expert
    for (int rr = wv * 16; rr < wv * 16 + 16; ++rr) {
      float v = red[rr * 64 + lane] + red[(64 + rr) * 64 + lane];
      part[((size_t)ks * N + r0 + rr) * 64 + lane] = v;
    }
  }
}

// Finalize: reduce split-K partials, softmax, top-2. Grid 4096 x 256 (wave/row).
__global__ __launch_bounds__(256) void finalize_kernel(
    const float* __restrict__ part,
    float* __restrict__ out_scores,
    float* __restrict__ out_w,
    float* __restrict__ out_i) {
  const int wv = threadIdx.x >> 6;
  const int lane = threadIdx.x & 63;
  const int row = blockIdx.x * 4 + wv;

  float v = part[(size_t)row * 64 + lane] +
            part[((size_t)N + row) * 64 + lane];
  v *= DESCALE;
  // softmax
  float m = v;
#pragma unroll
  for (int o = 32; o > 0; o >>= 1) m = fmaxf(m, __shfl_xor(m, o));
  float ev = __expf(v - m);
  float ssum = ev;
#pragma unroll
  for (int o = 32; o > 0; o >>= 1) ssum += __shfl_xor(ssum, o);
  out_scores[(size_t)row * E + lane] = ev / ssum;
  // top-2 butterfly with (value desc, index asc) order — matches lax.top_k
  float v1 = v;
  int i1 = lane;
  float v2 = -3.4e38f;
  int i2 = E;
#pragma unroll
  for (int o = 32; o > 0; o >>= 1) {
    float w1 = __shfl_xor(v1, o);
    int j1 = __shfl_xor(i1, o);
    float w2 = __shfl_xor(v2, o);
    int j2 = __shfl_xor(i2, o);
    bool firstBetter = (v1 > w1) || (v1 == w1 && i1 < j1);
    float t1, t2;
    int ti1, ti2;
    if (firstBetter) {
      t1 = v1; ti1 = i1;
      bool sec = (v2 > w1) || (v2 == w1 && i2 < j1);
      t2 = sec ? v2 : w1;
      ti2 = sec ? i2 : j1;
    } else {
      t1 = w1; ti1 = j1;
      bool sec = (w2 > v1) || (w2 == v1 && j2 < i1);
      t2 = sec ? w2 : v1;
      ti2 = sec ? j2 : i1;
    }
    v1 = t1; i1 = ti1; v2 = t2; i2 = ti2;
  }
  if (lane == 0) {
    float e1 = __expf(v1 - m);
    float e2 = __expf(v2 - m);
    float inv = 1.0f / (e1 + e2);
    size_t o2 = (size_t)row * 2;
    out_w[o2] = e1 * inv;
    out_w[o2 + 1] = e2 * inv;
    out_i[o2] = (float)i1;
    out_i[o2 + 1] = (float)i2;
  }
}

extern "C" void kernel_launch(void* const* d_in, const int* in_sizes, int n_in,
                              void* d_out, int out_size, void* d_ws, size_t ws_size,
                              hipStream_t stream) {
  const float* x = (const float*)d_in[0];
  const float* W = (const float*)d_in[1];
  float* out = (float*)d_out;
  float* out_scores = out;                  // [N, 64]
  float* out_w = out + (size_t)N * E;       // [N, 2]
  float* out_i = out_w + (size_t)N * 2;     // [N, 2] (indices as floats)
  _Float16* Whi = (_Float16*)d_ws;          // 512 KB
  _Float16* Wlo = Whi + (size_t)E * H;      // 512 KB
  float* part = (float*)((char*)d_ws + 2 * 1024 * 1024);  // [KS][N][E] = 8 MB

  wsplit_kernel<<<(E * H + 255) / 256, 256, 0, stream>>>(W, Whi, Wlo);
  gemm_kernel<<<(N / BM) * KS, 512, 0, stream>>>(x, Whi, Wlo, part);
  finalize_kernel<<<N / 4, 256, 0, stream>>>(part, out_scores, out_w, out_i);
}